// Round 9
// baseline (153.953 us; speedup 1.0000x reference)
//
#include <hip/hip_runtime.h>
#include <hip/hip_bf16.h>
#include <math.h>

// Problem constants (fixed by the reference)
#define NPTS 50000   // N data points
#define DIM  256     // feature dim (K of the GEMM)
#define BQ   2048    // batch of queries (M of the GEMM)
#define NPAD 50048   // N padded to multiple of 128

#define BK   32
#define CH   32      // n-rows per LDS chunk (16 KB per buffer)
#define NCH32 1564   // NPAD/CH
#define NG   64      // n-groups; grid = 8 m-tiles x 64 = 512 = 2 blocks/CU
                     // (register-limited). 64%8==0 -> b%8 = g%8: all 8
                     // m-tiles of a group share one XCD (B L2-resident).
#define LOG2E 1.4426950408889634f

// ---------- fast-path ws layout (float offsets) ----------
//  acc   [0,      2048)
//  x2h   [2048,   4096)   0.5*log2e*||x||^2
//  t     [4096,  54144)   0.5*log2e*||s||^2 - log2|w|  (+inf when w==0)
//  sgn   [54144, 104192)  label sign
//  xb    [104192, 366336)   bf16 x
//  sb    [366336, 6772480)  bf16 s (NPAD rows, 0-padded)
#define WS_ACC 0
#define WS_X2  2048
#define WS_T   4096
#define WS_SGN 54144
#define WS_XB  104192
#define WS_SB  366336
#define WS_TOTAL_BYTES (6772480ull * 4ull)  // 27,089,920 B

// ---------- v1 fallback ws layout ----------
#define V1_ACC 0
#define V1_X2  2048
#define V1_S2  4096
#define V1_W   54096

typedef __bf16 bf16x8 __attribute__((ext_vector_type(8)));
typedef __bf16 bf16x4 __attribute__((ext_vector_type(4)));
typedef float  f32x4  __attribute__((ext_vector_type(4)));
typedef unsigned int u32;

__device__ __forceinline__ float fast_exp2(float v) {
#if __has_builtin(__builtin_amdgcn_exp2f)
  return __builtin_amdgcn_exp2f(v);   // raw v_exp_f32
#else
  return exp2f(v);
#endif
}

__device__ __forceinline__ void async_copy16(const __bf16* g, __bf16* l) {
  __builtin_amdgcn_global_load_lds(
      (const __attribute__((address_space(1))) u32*)g,
      (__attribute__((address_space(3))) u32*)l, 16, 0, 0);
}

// ============================================================
// FAST PATH (bf16, verified line)
// ============================================================

// One wave per row: fp32->bf16 convert into ws, plus folded epilogue
// constants t = s2h - log2|w| and sign. Blocks 0..7 zero the accumulator.
__global__ __launch_bounds__(256) void svm_precvt9(
    const float* __restrict__ x, const float* __restrict__ s,
    const float* __restrict__ labels, const float* __restrict__ lambdas,
    float* __restrict__ ws) {
  const int wid  = blockIdx.x * 4 + (threadIdx.x >> 6);
  const int lane = threadIdx.x & 63;
  __bf16* xb = (__bf16*)(ws + WS_XB);
  __bf16* sb = (__bf16*)(ws + WS_SB);

  if (blockIdx.x < 8) ws[WS_ACC + blockIdx.x * 256 + threadIdx.x] = 0.0f;

  if (wid < NPAD) {
    float4 v = make_float4(0.f, 0.f, 0.f, 0.f);
    if (wid < NPTS)
      v = reinterpret_cast<const float4*>(s + (size_t)wid * DIM)[lane];
    bf16x4 h = { (__bf16)v.x, (__bf16)v.y, (__bf16)v.z, (__bf16)v.w };
    *reinterpret_cast<bf16x4*>(sb + (size_t)wid * DIM + lane * 4) = h;
    float ss = v.x * v.x + v.y * v.y + v.z * v.z + v.w * v.w;
    #pragma unroll
    for (int off = 32; off > 0; off >>= 1) ss += __shfl_xor(ss, off);
    if (lane == 0) {
      float s2h = 0.5f * LOG2E * ss;
      float lam = (wid < NPTS) ? lambdas[wid] : 0.0f;
      float lab = (wid < NPTS) ? labels[wid] : 1.0f;
      float mag = lam > 0.0f ? lam : 0.0f;
      ws[WS_T + wid]   = (mag > 0.0f) ? s2h - log2f(mag) : __builtin_inff();
      ws[WS_SGN + wid] = lab;
    }
  } else if (wid < NPAD + BQ) {
    int r = wid - NPAD;
    float4 v = reinterpret_cast<const float4*>(x + (size_t)r * DIM)[lane];
    bf16x4 h = { (__bf16)v.x, (__bf16)v.y, (__bf16)v.z, (__bf16)v.w };
    *reinterpret_cast<bf16x4*>(xb + (size_t)r * DIM + lane * 4) = h;
    float ss = v.x * v.x + v.y * v.y + v.z * v.z + v.w * v.w;
    #pragma unroll
    for (int off = 32; off > 0; off >>= 1) ss += __shfl_xor(ss, off);
    if (lane == 0) ws[WS_X2 + r] = 0.5f * LOG2E * ss;
  }
}

// main19 = main15's data path (mi=4/ni=2, afr pinned, identical swizzles,
// identical inner loop) with T4 done PROPERLY: tri-buffered LDS (3x16 KB),
// stage issued 2 CHUNKS AHEAD, and NO vmcnt(0) anywhere in the main loop.
// Five schedules all plateaued at ~62-65 us = the documented m97-structure
// ceiling; m218 says the breaking ingredient is counted-vmcnt (drain0 vs
// counted = +38-73%). Mechanism here: buffer c+1's readiness comes free
// from the epilogue's compiler-counted wait on tt/sg (issue order pinned:
// tt/sg BEFORE stage c+2 via sched_barrier(0) -> waiting tt/sg == vmcnt(4)
// => c+1 landed, c+2 still in flight). Raw s_barrier (no waitcnt drain)
// bounds wave drift to <1 iteration, which 3 buffers tolerate (writer of
// buf[(c+2)%3] vs its last reader at chunk c-1 are 1+ barrier apart).
// Per-wave vmcnt covers own gll; the barrier extends it to all waves.
// Stage loads get ~2 chunks (~5000 cyc) of slack instead of ~2000.
__global__ __launch_bounds__(256, 2) void svm_main19(float* __restrict__ ws) {
  // [buf][kt][n=32][32k] with 16B slot swizzle: slot(n,c) = c ^ ((n>>1)&3)
  __shared__ __bf16 sB[3][8 * CH * 32];  // 3 x 16 KB ring

  const __bf16* xb = (const __bf16*)(ws + WS_XB);
  const __bf16* sb = (const __bf16*)(ws + WS_SB);
  const float* x2g = ws + WS_X2;
  const float* tg  = ws + WS_T;
  const float* sgg = ws + WS_SGN;
  float* accOut    = ws + WS_ACC;

  const int t    = threadIdx.x;
  const int wave = t >> 6;            // 0..3
  const int lane = t & 63;
  const int quad = lane >> 4;
  const int l16  = lane & 15;
  const int g    = blockIdx.x & (NG - 1);  // n-group 0..63 (pow2: exact)
  const int mt   = blockIdx.x >> 6;        // m-tile 0..7 (256 rows each)
  const int m0   = mt * 256;
  const int c0   = (NCH32 * g) / NG;
  const int c1   = (NCH32 * (g + 1)) / NG;  // c1-c0 = 24 or 25 always

  // staging source swizzle (lane-only): slot fetched = (l&3) ^ ((l>>3)&3)
  const int srcswz = ((lane & 3) ^ ((lane >> 3) & 3)) * 8;  // bf16 elems
  // read-side swizzled 16B slot for this lane's B fragment
  const int rdswz = (quad ^ ((l16 >> 1) & 3)) * 8;          // bf16 elems

#define STAGE19(buf, cc)                                                      \
  do {                                                                        \
    _Pragma("unroll")                                                         \
    for (int i = 0; i < 4; ++i) {                                             \
      int chn = wave * 4 + i;            /* 0..15 */                          \
      int kt = chn >> 1;                 /* 0..7  */                          \
      int nb = (chn & 1) * 16;           /* 0,16  */                          \
      const __bf16* src = sb + (size_t)((cc) * CH + nb + (lane >> 2)) * DIM   \
                             + kt * BK + srcswz;                              \
      async_copy16(src, &sB[(buf)][kt * (CH * 32) + nb * 32] + lane * 8);     \
    }                                                                         \
  } while (0)

  // Prologue: stage c0 and c0+1 (c1-c0 >= 24 so both exist).
  STAGE19(0, c0);
  STAGE19(1, c0 + 1);

  // A fragments: 4 mi x 8 kt x 16 B = 128 VGPR, loaded once, pinned opaque.
  // (the "+v" pin forces afr values resident -> compiler waits their loads)
  f32x4 afr[4][8];
  #pragma unroll
  for (int mi = 0; mi < 4; ++mi)
    #pragma unroll
    for (int kt = 0; kt < 8; ++kt)
      afr[mi][kt] = *reinterpret_cast<const f32x4*>(
          xb + (size_t)(m0 + wave * 64 + mi * 16 + l16) * DIM + kt * BK + quad * 8);
  #pragma unroll
  for (int mi = 0; mi < 4; ++mi)
    #pragma unroll
    for (int kt = 0; kt < 8; ++kt)
      asm volatile("" : "+v"(afr[mi][kt]));  // no remat, stays in VGPRs

  float runAcc[4][4] = {{0.f, 0.f, 0.f, 0.f}, {0.f, 0.f, 0.f, 0.f},
                        {0.f, 0.f, 0.f, 0.f}, {0.f, 0.f, 0.f, 0.f}};

  // Counted wait: c0's 4 gll done, c0+1's 4 may stay in flight.
  asm volatile("s_waitcnt vmcnt(4)" ::: "memory");
  __builtin_amdgcn_s_barrier();

  int cur = 0;  // ring index of the chunk being computed
  for (int c = c0; c < c1; ++c) {
    // (1) tt/sg for THIS chunk — ordinary loads; their consumer wait in the
    //     epilogue is the counted vmcnt that also certifies stage c+1.
    float tt[2], sg[2];
    #pragma unroll
    for (int ni = 0; ni < 2; ++ni) {
      int n = c * CH + ni * 16 + l16;
      tt[ni] = tg[n];
      sg[ni] = sgg[n];
    }
    // Pin issue order: tt/sg BEFORE stage c+2, so waiting on tt/sg is a
    // COUNTED wait (4 younger gll in flight), never a drain.
    __builtin_amdgcn_sched_barrier(0);

    // (2) Stage chunk c+2 into ring slot (cur+2)%3. Its last reader (as
    //     chunk c-1) finished before the barrier that ended iter c-1.
    {
      int c2 = c + 2;
      if (c2 < c1) {
        int b2 = cur + 2; if (b2 >= 3) b2 -= 3;
        STAGE19(b2, c2);
      }
    }

    // (3) Compute current chunk from sB[cur] (compiler-scheduled fine lgkm).
    f32x4 acc[4][2];
    #pragma unroll
    for (int mi = 0; mi < 4; ++mi)
      #pragma unroll
      for (int ni = 0; ni < 2; ++ni)
        acc[mi][ni] = (f32x4)(0.0f);

    const __bf16* bufB = &sB[cur][0];
    #pragma unroll
    for (int kt = 0; kt < 8; ++kt) {
      bf16x8 bfv[2];
      #pragma unroll
      for (int ni = 0; ni < 2; ++ni)
        bfv[ni] = *reinterpret_cast<const bf16x8*>(
            bufB + kt * (CH * 32) + (ni * 16 + l16) * 32 + rdswz);
      #pragma unroll
      for (int mi = 0; mi < 4; ++mi)
        #pragma unroll
        for (int ni = 0; ni < 2; ++ni)
          acc[mi][ni] = __builtin_amdgcn_mfma_f32_16x16x32_bf16(
              __builtin_bit_cast(bf16x8, afr[mi][kt]), bfv[ni],
              acc[mi][ni], 0, 0, 0);
    }

    // (4) Epilogue: consumes tt/sg -> compiler inserts vmcnt(4): stage c+1
    //     (older than tt/sg) certified complete; stage c+2 stays in flight.
    #pragma unroll
    for (int mi = 0; mi < 4; ++mi)
      #pragma unroll
      for (int reg = 0; reg < 4; ++reg) {
        float p = runAcc[mi][reg];
        #pragma unroll
        for (int ni = 0; ni < 2; ++ni)
          p = __builtin_fmaf(sg[ni],
                fast_exp2(__builtin_fmaf(acc[mi][ni][reg], LOG2E, -tt[ni])), p);
        runAcc[mi][reg] = p;
      }

    // (5) Raw barrier — NO waitcnt drain. Every wave already certified its
    //     own c+1 gll (step 4); the barrier extends that to all waves and
    //     bounds drift so step (2) of iter c+1 can't race a slow reader.
    __builtin_amdgcn_s_barrier();
    asm volatile("" ::: "memory");
    cur = (cur + 1 < 3) ? cur + 1 : 0;
  }

  // reduce over the 16 n-column lanes; scale by exp2(-x2h); one atomic/row.
  #pragma unroll
  for (int mi = 0; mi < 4; ++mi)
    #pragma unroll
    for (int reg = 0; reg < 4; ++reg) {
      float v = runAcc[mi][reg];
      v += __shfl_xor(v, 1);
      v += __shfl_xor(v, 2);
      v += __shfl_xor(v, 4);
      v += __shfl_xor(v, 8);
      if (l16 == 0) {
        int row = m0 + wave * 64 + mi * 16 + quad * 4 + reg;
        atomicAdd(&accOut[row], fast_exp2(-x2g[row]) * v);
      }
    }
#undef STAGE19
}

// ============================================================
// V1 FALLBACK (used only if ws_size too small)
// ============================================================

__global__ __launch_bounds__(256) void svm_precompute(
    const float* __restrict__ x, const float* __restrict__ s,
    const float* __restrict__ labels, const float* __restrict__ lambdas,
    float* __restrict__ ws) {
  int wid  = blockIdx.x * 4 + (threadIdx.x >> 6);
  int lane = threadIdx.x & 63;
  const float* src;
  if (wid < NPTS)           src = s + (size_t)wid * DIM;
  else if (wid < NPTS + BQ) src = x + (size_t)(wid - NPTS) * DIM;
  else return;
  float4 v = reinterpret_cast<const float4*>(src)[lane];
  float ss = v.x * v.x + v.y * v.y + v.z * v.z + v.w * v.w;
  #pragma unroll
  for (int off = 32; off > 0; off >>= 1) ss += __shfl_xor(ss, off);
  if (lane == 0) {
    if (wid < NPTS) {
      ws[V1_S2 + wid] = ss;
      float lam = lambdas[wid];
      ws[V1_W + wid] = labels[wid] * (lam > 0.0f ? lam : 0.0f);
    } else {
      ws[V1_X2 + (wid - NPTS)] = ss;
    }
  }
}

__global__ __launch_bounds__(256) void svm_main(
    const float* __restrict__ x, const float* __restrict__ s,
    const float* __restrict__ ws) {
  __shared__ __bf16 sA[128 * BK];
  __shared__ __bf16 sB2[128 * BK];

  const int t    = threadIdx.x;
  const int wave = t >> 6;
  const int lane = t & 63;
  const int quad = lane >> 4;
  const int l16  = lane & 15;
  const int wm   = (wave & 1) * 64;
  const int wn   = (wave >> 1) * 64;
  const int bRow0 = blockIdx.y * 128;
  const int n0    = blockIdx.x * 128;

  f32x4 acc[4][4];
  #pragma unroll
  for (int i = 0; i < 4; ++i)
    #pragma unroll
    for (int j = 0; j < 4; ++j)
      acc[i][j] = (f32x4)(0.0f);

  for (int kt = 0; kt < DIM / BK; ++kt) {
    const int k0 = kt * BK;
    __syncthreads();
    #pragma unroll
    for (int i = 0; i < 4; ++i) {
      int slot = t + i * 256;
      int r  = slot >> 3;
      int c4 = slot & 7;
      float4 va = reinterpret_cast<const float4*>(
          x + (size_t)(bRow0 + r) * DIM + k0)[c4];
      bf16x4 ha = { (__bf16)va.x, (__bf16)va.y, (__bf16)va.z, (__bf16)va.w };
      *reinterpret_cast<bf16x4*>(&sA[r * BK + c4 * 4]) = ha;

      int nrow = n0 + r;
      float4 vb = make_float4(0.f, 0.f, 0.f, 0.f);
      if (nrow < NPTS)
        vb = reinterpret_cast<const float4*>(
            s + (size_t)nrow * DIM + k0)[c4];
      bf16x4 hb = { (__bf16)vb.x, (__bf16)vb.y, (__bf16)vb.z, (__bf16)vb.w };
      *reinterpret_cast<bf16x4*>(&sB2[r * BK + c4 * 4]) = hb;
    }
    __syncthreads();

    bf16x8 af[4], bfv[4];
    #pragma unroll
    for (int mi = 0; mi < 4; ++mi)
      af[mi] = *reinterpret_cast<const bf16x8*>(
          &sA[(wm + mi * 16 + l16) * BK + quad * 8]);
    #pragma unroll
    for (int ni = 0; ni < 4; ++ni)
      bfv[ni] = *reinterpret_cast<const bf16x8*>(
          &sB2[(wn + ni * 16 + l16) * BK + quad * 8]);
    #pragma unroll
    for (int mi = 0; mi < 4; ++mi)
      #pragma unroll
      for (int ni = 0; ni < 4; ++ni)
        acc[mi][ni] = __builtin_amdgcn_mfma_f32_16x16x32_bf16(
            af[mi], bfv[ni], acc[mi][ni], 0, 0, 0);
  }

  const float* x2g = ws + V1_X2;
  const float* s2g = ws + V1_S2;
  const float* wg  = ws + V1_W;
  float* accOut    = (float*)ws + V1_ACC;

  float s2v[4], wv[4];
  #pragma unroll
  for (int ni = 0; ni < 4; ++ni) {
    int n = n0 + wn + ni * 16 + l16;
    bool ok = n < NPTS;
    s2v[ni] = ok ? s2g[n] : 0.0f;
    wv[ni]  = ok ? wg[n]  : 0.0f;
  }
  #pragma unroll
  for (int mi = 0; mi < 4; ++mi) {
    const int mbase = wm + mi * 16 + quad * 4;
    #pragma unroll
    for (int reg = 0; reg < 4; ++reg) {
      float x2r = x2g[bRow0 + mbase + reg];
      float ps = 0.0f;
      #pragma unroll
      for (int ni = 0; ni < 4; ++ni) {
        float cc = acc[mi][ni][reg];
        ps += __expf(__builtin_fmaf(-0.5f, x2r + s2v[ni], cc)) * wv[ni];
      }
      ps += __shfl_xor(ps, 1);
      ps += __shfl_xor(ps, 2);
      ps += __shfl_xor(ps, 4);
      ps += __shfl_xor(ps, 8);
      if (l16 == 0) atomicAdd(&accOut[bRow0 + mbase + reg], ps);
    }
  }
}

// ============================================================

__global__ __launch_bounds__(256) void svm_finalize(
    const float* __restrict__ ws, const float* __restrict__ bias,
    float* __restrict__ out) {
  int i = blockIdx.x * 256 + threadIdx.x;
  if (i < BQ) out[i] = tanhf(ws[i] + bias[0]);  // acc at offset 0 in all layouts
}

extern "C" void kernel_launch(void* const* d_in, const int* in_sizes, int n_in,
                              void* d_out, int out_size, void* d_ws, size_t ws_size,
                              hipStream_t stream) {
  const float* x       = (const float*)d_in[0];  // [2048, 256]
  const float* s       = (const float*)d_in[1];  // [50000, 256]
  const float* labels  = (const float*)d_in[2];  // [50000]
  const float* lambdas = (const float*)d_in[3];  // [50000]
  const float* bias    = (const float*)d_in[4];  // [1]
  float* out = (float*)d_out;                    // [2048]
  float* ws  = (float*)d_ws;

  if (ws_size >= WS_TOTAL_BYTES) {
    // precvt9 zeroes the accumulator region itself (blocks 0..7)
    svm_precvt9<<<(NPAD + BQ + 3) / 4, 256, 0, stream>>>(x, s, labels, lambdas, ws);
    svm_main19<<<8 * NG, 256, 0, stream>>>(ws);
  } else {
    hipMemsetAsync(ws, 0, BQ * sizeof(float), stream);
    svm_precompute<<<(NPTS + BQ + 3) / 4, 256, 0, stream>>>(x, s, labels, lambdas, ws);
    dim3 grid(391, BQ / 128);
    svm_main<<<grid, 256, 0, stream>>>(x, s, ws);
  }
  svm_finalize<<<BQ / 256, 256, 0, stream>>>(ws, bias, out);
}

// Round 10
// 144.925 us; speedup vs baseline: 1.0623x; 1.0623x over previous
//
#include <hip/hip_runtime.h>
#include <hip/hip_bf16.h>
#include <hip/hip_fp8.h>
#include <math.h>

// Problem constants (fixed by the reference)
#define NPTS 50000   // N data points
#define DIM  256     // feature dim (K of the GEMM)
#define BQ   2048    // batch of queries (M of the GEMM)
#define NPAD 50048   // N padded to multiple of 128

#define CH   32      // n-rows per chunk (8 KB fp8 per buffer)
#define NCH32 1564   // NPAD/CH
#define NG   64      // n-groups; grid = 8 m-tiles x 64 = 512 = 2 blocks/CU
                     // (register-limited). 64%8==0 -> b%8 = g%8: all 8
                     // m-tiles of a group share one XCD (B L2-resident).
#define LOG2E 1.4426950408889634f

// ---------- fast-path ws layout (float offsets; fp8 regions reuse the old
//            bf16 slots, which are 2x larger than needed) ----------
//  acc   [0,      2048)
//  x2h   [2048,   4096)   0.5*log2e*||x||^2
//  t     [4096,  54144)   0.5*log2e*||s||^2 - log2|w|  (+inf when w==0)
//  sgn   [54144, 104192)  label sign
//  xb8   [104192, ...)    fp8 e4m3 x   (2048*256 B)
//  sb8   [366336, ...)    fp8 e4m3 s   (NPAD*256 B, 0-padded)
#define WS_ACC 0
#define WS_X2  2048
#define WS_T   4096
#define WS_SGN 54144
#define WS_XB  104192
#define WS_SB  366336
#define WS_TOTAL_BYTES (6772480ull * 4ull)  // 27,089,920 B (gate unchanged)

// ---------- v1 fallback ws layout ----------
#define V1_ACC 0
#define V1_X2  2048
#define V1_S2  4096
#define V1_W   54096

typedef __bf16 bf16x8 __attribute__((ext_vector_type(8)));
typedef __bf16 bf16x4 __attribute__((ext_vector_type(4)));
typedef float  f32x4  __attribute__((ext_vector_type(4)));
typedef float  f32x16 __attribute__((ext_vector_type(16)));
typedef int    i32x4  __attribute__((ext_vector_type(4)));
typedef int    i32x8  __attribute__((ext_vector_type(8)));
typedef unsigned int u32;
typedef unsigned char u8;

__device__ __forceinline__ float fast_exp2(float v) {
#if __has_builtin(__builtin_amdgcn_exp2f)
  return __builtin_amdgcn_exp2f(v);   // raw v_exp_f32
#else
  return exp2f(v);
#endif
}

__device__ __forceinline__ void async_copy16(const void* g, void* l) {
  __builtin_amdgcn_global_load_lds(
      (const __attribute__((address_space(1))) u32*)g,
      (__attribute__((address_space(3))) u32*)l, 16, 0, 0);
}

// pack 4 floats -> 4 fp8 e4m3 bytes (k-order = byte order)
__device__ __forceinline__ u32 pack_fp8x4(float4 v) {
#if __has_builtin(__builtin_amdgcn_cvt_pk_fp8_f32)
  int pk = __builtin_amdgcn_cvt_pk_fp8_f32(v.x, v.y, 0, false);
  pk = __builtin_amdgcn_cvt_pk_fp8_f32(v.z, v.w, pk, true);
  return (u32)pk;
#else
  __hip_fp8_e4m3 a(v.x), b(v.y), c(v.z), d(v.w);
  return (u32)a.__x | ((u32)b.__x << 8) | ((u32)c.__x << 16) | ((u32)d.__x << 24);
#endif
}

// ============================================================
// FAST PATH (fp8 MX, 32x32x64 MFMA)
// ============================================================

// One wave per row: fp32->fp8 convert into ws, plus folded epilogue
// constants t = s2h - log2|w| and sign. Blocks 0..7 zero the accumulator.
__global__ __launch_bounds__(256) void svm_precvt10(
    const float* __restrict__ x, const float* __restrict__ s,
    const float* __restrict__ labels, const float* __restrict__ lambdas,
    float* __restrict__ ws) {
  const int wid  = blockIdx.x * 4 + (threadIdx.x >> 6);
  const int lane = threadIdx.x & 63;
  u8* xb8 = (u8*)(ws + WS_XB);
  u8* sb8 = (u8*)(ws + WS_SB);

  if (blockIdx.x < 8) ws[WS_ACC + blockIdx.x * 256 + threadIdx.x] = 0.0f;

  if (wid < NPAD) {
    float4 v = make_float4(0.f, 0.f, 0.f, 0.f);
    if (wid < NPTS)
      v = reinterpret_cast<const float4*>(s + (size_t)wid * DIM)[lane];
    ((u32*)(sb8 + (size_t)wid * DIM))[lane] = pack_fp8x4(v);
    float ss = v.x * v.x + v.y * v.y + v.z * v.z + v.w * v.w;
    #pragma unroll
    for (int off = 32; off > 0; off >>= 1) ss += __shfl_xor(ss, off);
    if (lane == 0) {
      float s2h = 0.5f * LOG2E * ss;
      float lam = (wid < NPTS) ? lambdas[wid] : 0.0f;
      float lab = (wid < NPTS) ? labels[wid] : 1.0f;
      float mag = lam > 0.0f ? lam : 0.0f;
      ws[WS_T + wid]   = (mag > 0.0f) ? s2h - log2f(mag) : __builtin_inff();
      ws[WS_SGN + wid] = lab;
    }
  } else if (wid < NPAD + BQ) {
    int r = wid - NPAD;
    float4 v = reinterpret_cast<const float4*>(x + (size_t)r * DIM)[lane];
    ((u32*)(xb8 + (size_t)r * DIM))[lane] = pack_fp8x4(v);
    float ss = v.x * v.x + v.y * v.y + v.z * v.z + v.w * v.w;
    #pragma unroll
    for (int off = 32; off > 0; off >>= 1) ss += __shfl_xor(ss, off);
    if (lane == 0) ws[WS_X2 + r] = 0.5f * LOG2E * ss;
  }
}

// main20: after six null scheduling rounds (61-65 us invariant), shrink the
// per-wave serial chain itself: fp8 e4m3 + mfma_scale_f32_32x32x64_f8f6f4
// (scales=1.0; m59 ubench 4686 TF = 2x bf16 rate). Per wave per chunk vs
// main19: MFMA pipe 1242->550 cyc (8 insts), ds_read 16->8 b128 (8 KB
// chunk), stage 4->2 gll, tt/sg 4->2 loads (32x32 C layout: col=lane&31 ->
// tt/sg are SCALAR per lane), afr 128->64 VGPR. Layouts: A/B frag row|col
// = l&31, k = (l>>5)*32+j (verified 32x32 family); C/D col=lane&31,
// row=(reg&3)+8*(reg>>2)+4*(lane>>5) (dtype-independent, m121-128).
// LDS swizzle: phys16Bslot = (r<<2|q) ^ ((r>>1)&3) — hand-traced
// write/read pairs; <=2-way conflicts (free, m136). Loop = main19's
// ring-3 counted-vmcnt schedule, unchanged.
__global__ __launch_bounds__(256, 2) void svm_main20(float* __restrict__ ws) {
  __shared__ u8 sB[3][8192];  // 3 x 8 KB ring, [kt4][row32 x 64B swizzled]

  const u8* xb8 = (const u8*)(ws + WS_XB);
  const u8* sb8 = (const u8*)(ws + WS_SB);
  const float* x2g = ws + WS_X2;
  const float* tg  = ws + WS_T;
  const float* sgg = ws + WS_SGN;
  float* accOut    = ws + WS_ACC;

  const int t    = threadIdx.x;
  const int wave = t >> 6;            // 0..3
  const int lane = t & 63;
  const int l32  = lane & 31;
  const int hk   = lane >> 5;         // k-half selector
  const int g    = blockIdx.x & (NG - 1);  // n-group 0..63 (pow2: exact)
  const int mt   = blockIdx.x >> 6;        // m-tile 0..7 (256 rows each)
  const int m0   = mt * 256;
  const int c0   = (NCH32 * g) / NG;
  const int c1   = (NCH32 * (g + 1)) / NG;  // 24 or 25 chunks

  // Stage chunk cc into buf: 2 gll per wave (8 x 1KB per block).
  // gll p = wave*2+i: kt = p>>1, h = p&1; lane writes phys slot h*64+lane.
  // Inverse of phys = (r<<2|q) ^ ((r>>1)&3): r = phys>>2,
  // q = (phys&3) ^ ((r>>1)&3).
#define STAGE20(buf, cc)                                                      \
  do {                                                                        \
    _Pragma("unroll")                                                         \
    for (int i = 0; i < 2; ++i) {                                             \
      int p  = wave * 2 + i;             /* 0..7 */                           \
      int kt = p >> 1;                   /* 0..3 */                           \
      int h  = p & 1;                                                         \
      int r  = h * 16 + (lane >> 2);                                          \
      int q  = (lane & 3) ^ ((r >> 1) & 3);                                   \
      const u8* src = sb8 + (size_t)((cc) * CH + r) * DIM + kt * 64 + q * 16; \
      async_copy16(src, &sB[(buf)][kt * 2048 + h * 1024 + lane * 16]);        \
    }                                                                         \
  } while (0)

  // Prologue: stage c0 and c0+1.
  STAGE20(0, c0);
  STAGE20(1, c0 + 1);

  // A fragments: 2 mi x 4 kt x 32 B = 64 VGPR, loaded once, pinned opaque.
  // lane holds A[row = m-block + l32][k = kt*64 + hk*32 .. +32).
  i32x8 afr[2][4];
  #pragma unroll
  for (int mi = 0; mi < 2; ++mi)
    #pragma unroll
    for (int kt = 0; kt < 4; ++kt) {
      const u8* ap = xb8 + (size_t)(m0 + wave * 64 + mi * 32 + l32) * DIM
                         + kt * 64 + hk * 32;
      i32x4 a0 = *reinterpret_cast<const i32x4*>(ap);
      i32x4 a1 = *reinterpret_cast<const i32x4*>(ap + 16);
      afr[mi][kt] = __builtin_shufflevector(a0, a1, 0, 1, 2, 3, 4, 5, 6, 7);
    }
  #pragma unroll
  for (int mi = 0; mi < 2; ++mi)
    #pragma unroll
    for (int kt = 0; kt < 4; ++kt)
      asm volatile("" : "+v"(afr[mi][kt]));  // no remat, stays in VGPRs

  float runAcc0[16], runAcc1[16];
  #pragma unroll
  for (int i = 0; i < 16; ++i) { runAcc0[i] = 0.0f; runAcc1[i] = 0.0f; }

  // Counted wait: c0's gll done; c0+1 may stay in flight (2 newest afr
  // loads too — their first use waits them).
  asm volatile("s_waitcnt vmcnt(2)" ::: "memory");
  __builtin_amdgcn_s_barrier();

  int cur = 0;
  for (int c = c0; c < c1; ++c) {
    // (1) Per-lane epilogue constants (col = c*32 + l32). Their consumer
    //     wait in the epilogue is the counted vmcnt certifying stage c+1.
    float tt = tg[c * CH + l32];
    float sg = sgg[c * CH + l32];
    __builtin_amdgcn_sched_barrier(0);  // pin: tt/sg issued BEFORE stage c+2

    // (2) Stage chunk c+2 (ring slot cur+2; its last reader finished
    //     before the barrier that ended iteration c-1).
    {
      int c2 = c + 2;
      if (c2 < c1) {
        int b2 = cur + 2; if (b2 >= 3) b2 -= 3;
        STAGE20(b2, c2);
      }
    }

    // (3) Compute: 8 x mfma 32x32x64 fp8 (scales = 1.0 via 0x7F bytes).
    f32x16 acc0 = (f32x16)(0.0f), acc1 = (f32x16)(0.0f);
    const u8* bufB = &sB[cur][0];
    #pragma unroll
    for (int kt = 0; kt < 4; ++kt) {
      // lane reads B[col = l32][k = kt*64 + hk*32 .. +32): 2 x b128 at
      // swizzled slots s0, s0^1.
      int s0 = ((l32 << 2) | (hk << 1)) ^ ((l32 >> 1) & 3);
      const u8* bp = bufB + kt * 2048;
      i32x4 lo = *reinterpret_cast<const i32x4*>(bp + s0 * 16);
      i32x4 hi = *reinterpret_cast<const i32x4*>(bp + (s0 ^ 1) * 16);
      i32x8 bfr = __builtin_shufflevector(lo, hi, 0, 1, 2, 3, 4, 5, 6, 7);
      acc0 = __builtin_amdgcn_mfma_scale_f32_32x32x64_f8f6f4(
          afr[0][kt], bfr, acc0, 0, 0, 0, 0x7F7F7F7F, 0, 0x7F7F7F7F);
      acc1 = __builtin_amdgcn_mfma_scale_f32_32x32x64_f8f6f4(
          afr[1][kt], bfr, acc1, 0, 0, 0, 0x7F7F7F7F, 0, 0x7F7F7F7F);
    }

    // (4) Epilogue: p += sgn * exp2(dot*log2e - t). tt/sg scalar per lane
    //     (col fixed per lane in the 32x32 C layout). Consuming tt here
    //     inserts the counted vmcnt that certifies stage c+1 landed.
    #pragma unroll
    for (int reg = 0; reg < 16; ++reg)
      runAcc0[reg] = __builtin_fmaf(
          sg, fast_exp2(__builtin_fmaf(acc0[reg], LOG2E, -tt)), runAcc0[reg]);
    #pragma unroll
    for (int reg = 0; reg < 16; ++reg)
      runAcc1[reg] = __builtin_fmaf(
          sg, fast_exp2(__builtin_fmaf(acc1[reg], LOG2E, -tt)), runAcc1[reg]);

    // (5) Raw barrier — no waitcnt drain (main19-verified schedule).
    __builtin_amdgcn_s_barrier();
    asm volatile("" ::: "memory");
    cur = (cur + 1 < 3) ? cur + 1 : 0;
  }

  // Reduce over the 32 n-columns (lanes l32); one atomic per output row.
  // row = m0 + wave*64 + mi*32 + (reg&3) + 8*(reg>>2) + 4*hk.
  #pragma unroll
  for (int reg = 0; reg < 16; ++reg) {
    float v = runAcc0[reg];
    v += __shfl_xor(v, 1);
    v += __shfl_xor(v, 2);
    v += __shfl_xor(v, 4);
    v += __shfl_xor(v, 8);
    v += __shfl_xor(v, 16);
    if (l32 == 0) {
      int row = m0 + wave * 64 + (reg & 3) + 8 * (reg >> 2) + 4 * hk;
      atomicAdd(&accOut[row], fast_exp2(-x2g[row]) * v);
    }
  }
  #pragma unroll
  for (int reg = 0; reg < 16; ++reg) {
    float v = runAcc1[reg];
    v += __shfl_xor(v, 1);
    v += __shfl_xor(v, 2);
    v += __shfl_xor(v, 4);
    v += __shfl_xor(v, 8);
    v += __shfl_xor(v, 16);
    if (l32 == 0) {
      int row = m0 + wave * 64 + 32 + (reg & 3) + 8 * (reg >> 2) + 4 * hk;
      atomicAdd(&accOut[row], fast_exp2(-x2g[row]) * v);
    }
  }
#undef STAGE20
}

// ============================================================
// V1 FALLBACK (used only if ws_size too small)
// ============================================================

#define BK 32

__global__ __launch_bounds__(256) void svm_precompute(
    const float* __restrict__ x, const float* __restrict__ s,
    const float* __restrict__ labels, const float* __restrict__ lambdas,
    float* __restrict__ ws) {
  int wid  = blockIdx.x * 4 + (threadIdx.x >> 6);
  int lane = threadIdx.x & 63;
  const float* src;
  if (wid < NPTS)           src = s + (size_t)wid * DIM;
  else if (wid < NPTS + BQ) src = x + (size_t)(wid - NPTS) * DIM;
  else return;
  float4 v = reinterpret_cast<const float4*>(src)[lane];
  float ss = v.x * v.x + v.y * v.y + v.z * v.z + v.w * v.w;
  #pragma unroll
  for (int off = 32; off > 0; off >>= 1) ss += __shfl_xor(ss, off);
  if (lane == 0) {
    if (wid < NPTS) {
      ws[V1_S2 + wid] = ss;
      float lam = lambdas[wid];
      ws[V1_W + wid] = labels[wid] * (lam > 0.0f ? lam : 0.0f);
    } else {
      ws[V1_X2 + (wid - NPTS)] = ss;
    }
  }
}

__global__ __launch_bounds__(256) void svm_main(
    const float* __restrict__ x, const float* __restrict__ s,
    const float* __restrict__ ws) {
  __shared__ __bf16 sA[128 * BK];
  __shared__ __bf16 sB2[128 * BK];

  const int t    = threadIdx.x;
  const int wave = t >> 6;
  const int lane = t & 63;
  const int quad = lane >> 4;
  const int l16  = lane & 15;
  const int wm   = (wave & 1) * 64;
  const int wn   = (wave >> 1) * 64;
  const int bRow0 = blockIdx.y * 128;
  const int n0    = blockIdx.x * 128;

  f32x4 acc[4][4];
  #pragma unroll
  for (int i = 0; i < 4; ++i)
    #pragma unroll
    for (int j = 0; j < 4; ++j)
      acc[i][j] = (f32x4)(0.0f);

  for (int kt = 0; kt < DIM / BK; ++kt) {
    const int k0 = kt * BK;
    __syncthreads();
    #pragma unroll
    for (int i = 0; i < 4; ++i) {
      int slot = t + i * 256;
      int r  = slot >> 3;
      int c4 = slot & 7;
      float4 va = reinterpret_cast<const float4*>(
          x + (size_t)(bRow0 + r) * DIM + k0)[c4];
      bf16x4 ha = { (__bf16)va.x, (__bf16)va.y, (__bf16)va.z, (__bf16)va.w };
      *reinterpret_cast<bf16x4*>(&sA[r * BK + c4 * 4]) = ha;

      int nrow = n0 + r;
      float4 vb = make_float4(0.f, 0.f, 0.f, 0.f);
      if (nrow < NPTS)
        vb = reinterpret_cast<const float4*>(
            s + (size_t)nrow * DIM + k0)[c4];
      bf16x4 hb = { (__bf16)vb.x, (__bf16)vb.y, (__bf16)vb.z, (__bf16)vb.w };
      *reinterpret_cast<bf16x4*>(&sB2[r * BK + c4 * 4]) = hb;
    }
    __syncthreads();

    bf16x8 af[4], bfv[4];
    #pragma unroll
    for (int mi = 0; mi < 4; ++mi)
      af[mi] = *reinterpret_cast<const bf16x8*>(
          &sA[(wm + mi * 16 + l16) * BK + quad * 8]);
    #pragma unroll
    for (int ni = 0; ni < 4; ++ni)
      bfv[ni] = *reinterpret_cast<const bf16x8*>(
          &sB2[(wn + ni * 16 + l16) * BK + quad * 8]);
    #pragma unroll
    for (int mi = 0; mi < 4; ++mi)
      #pragma unroll
      for (int ni = 0; ni < 4; ++ni)
        acc[mi][ni] = __builtin_amdgcn_mfma_f32_16x16x32_bf16(
            af[mi], bfv[ni], acc[mi][ni], 0, 0, 0);
  }

  const float* x2g = ws + V1_X2;
  const float* s2g = ws + V1_S2;
  const float* wg  = ws + V1_W;
  float* accOut    = (float*)ws + V1_ACC;

  float s2v[4], wv[4];
  #pragma unroll
  for (int ni = 0; ni < 4; ++ni) {
    int n = n0 + wn + ni * 16 + l16;
    bool ok = n < NPTS;
    s2v[ni] = ok ? s2g[n] : 0.0f;
    wv[ni]  = ok ? wg[n]  : 0.0f;
  }
  #pragma unroll
  for (int mi = 0; mi < 4; ++mi) {
    const int mbase = wm + mi * 16 + quad * 4;
    #pragma unroll
    for (int reg = 0; reg < 4; ++reg) {
      float x2r = x2g[bRow0 + mbase + reg];
      float ps = 0.0f;
      #pragma unroll
      for (int ni = 0; ni < 4; ++ni) {
        float cc = acc[mi][ni][reg];
        ps += __expf(__builtin_fmaf(-0.5f, x2r + s2v[ni], cc)) * wv[ni];
      }
      ps += __shfl_xor(ps, 1);
      ps += __shfl_xor(ps, 2);
      ps += __shfl_xor(ps, 4);
      ps += __shfl_xor(ps, 8);
      if (l16 == 0) atomicAdd(&accOut[bRow0 + mbase + reg], ps);
    }
  }
}

// ============================================================

__global__ __launch_bounds__(256) void svm_finalize(
    const float* __restrict__ ws, const float* __restrict__ bias,
    float* __restrict__ out) {
  int i = blockIdx.x * 256 + threadIdx.x;
  if (i < BQ) out[i] = tanhf(ws[i] + bias[0]);  // acc at offset 0 in all layouts
}

extern "C" void kernel_launch(void* const* d_in, const int* in_sizes, int n_in,
                              void* d_out, int out_size, void* d_ws, size_t ws_size,
                              hipStream_t stream) {
  const float* x       = (const float*)d_in[0];  // [2048, 256]
  const float* s       = (const float*)d_in[1];  // [50000, 256]
  const float* labels  = (const float*)d_in[2];  // [50000]
  const float* lambdas = (const float*)d_in[3];  // [50000]
  const float* bias    = (const float*)d_in[4];  // [1]
  float* out = (float*)d_out;                    // [2048]
  float* ws  = (float*)d_ws;

  if (ws_size >= WS_TOTAL_BYTES) {
    // precvt10 zeroes the accumulator region itself (blocks 0..7)
    svm_precvt10<<<(NPAD + BQ + 3) / 4, 256, 0, stream>>>(x, s, labels, lambdas, ws);
    svm_main20<<<8 * NG, 256, 0, stream>>>(ws);
  } else {
    hipMemsetAsync(ws, 0, BQ * sizeof(float), stream);
    svm_precompute<<<(NPTS + BQ + 3) / 4, 256, 0, stream>>>(x, s, labels, lambdas, ws);
    dim3 grid(391, BQ / 128);
    svm_main<<<grid, 256, 0, stream>>>(x, s, ws);
  }
  svm_finalize<<<BQ / 256, 256, 0, stream>>>(ws, bias, out);
}